// Round 4
// baseline (171.188 us; speedup 1.0000x reference)
//
#include <hip/hip_runtime.h>
#include <stdint.h>

// ---------- types ----------
typedef __bf16 bf16x8 __attribute__((ext_vector_type(8)));
typedef float f32x4 __attribute__((ext_vector_type(4)));
typedef float float4v __attribute__((ext_vector_type(4)));
typedef unsigned short u16x8 __attribute__((ext_vector_type(8)));
typedef unsigned int u32x4 __attribute__((ext_vector_type(4)));

// round-to-nearest-even fp32 -> bf16
__device__ __forceinline__ unsigned short f2bf(float f) {
    unsigned u = __float_as_uint(f);
    u += 0x7fffu + ((u >> 16) & 1u);
    return (unsigned short)(u >> 16);
}

// fast stable softplus: max(x,0) + log(1+exp(-|x|))
__device__ __forceinline__ float softplus(float x) {
    return fmaxf(x, 0.0f) + __logf(1.0f + __expf(-fabsf(x)));
}

// ---------- fused prep: input f32->bf16  AND  w = mu + softplus(rho)*eps ----
__global__ void prep_kernel(const float* __restrict__ in,
                            const float* __restrict__ mu,
                            const float* __restrict__ rho,
                            const float* __restrict__ eps,
                            unsigned short* __restrict__ in_bf,
                            unsigned short* __restrict__ w_bf,
                            int nIn8, int nW8) {
    int i = blockIdx.x * blockDim.x + threadIdx.x;
    if (i < nIn8) {
        const float4v* p = (const float4v*)in + (size_t)i * 2;
        float4v a = p[0], b = p[1];
        u16x8 r;
        r[0] = f2bf(a[0]); r[1] = f2bf(a[1]); r[2] = f2bf(a[2]); r[3] = f2bf(a[3]);
        r[4] = f2bf(b[0]); r[5] = f2bf(b[1]); r[6] = f2bf(b[2]); r[7] = f2bf(b[3]);
        ((u16x8*)in_bf)[i] = r;
    } else {
        int j = i - nIn8;
        if (j >= nW8) return;
        const float4v* pm = (const float4v*)mu  + (size_t)j * 2;
        const float4v* pr = (const float4v*)rho + (size_t)j * 2;
        const float4v* pe = (const float4v*)eps + (size_t)j * 2;
        float4v m0 = pm[0], m1 = pm[1];
        float4v r0 = pr[0], r1 = pr[1];
        float4v e0 = pe[0], e1 = pe[1];
        u16x8 r;
        r[0] = f2bf(m0[0] + softplus(r0[0]) * e0[0]);
        r[1] = f2bf(m0[1] + softplus(r0[1]) * e0[1]);
        r[2] = f2bf(m0[2] + softplus(r0[2]) * e0[2]);
        r[3] = f2bf(m0[3] + softplus(r0[3]) * e0[3]);
        r[4] = f2bf(m1[0] + softplus(r1[0]) * e1[0]);
        r[5] = f2bf(m1[1] + softplus(r1[1]) * e1[1]);
        r[6] = f2bf(m1[2] + softplus(r1[2]) * e1[2]);
        r[7] = f2bf(m1[3] + softplus(r1[3]) * e1[3]);
        ((u16x8*)w_bf)[j] = r;
    }
}

// ---------- GEMM: C[M,N] = A[M,K] * B[N,K]^T + bias, bf16 in / f32 out -----
// R4 structure: tile 128x64, BK=64, 256 threads = 4 waves 2(m)x2(n),
// wave-tile 64x32 (4x2 MFMA 16x16x32). Grid (N/64)x(M/128) = 32x32 = 1024
// blocks -> 4 blocks/CU (LDS 24 KB single buffer allows 6; grid caps at 4),
// 16 waves/CU in FOUR independent barrier groups (vs two in R3).
// REGISTER PREFETCH replaces global_load_lds: tile i+1 is loaded global->VGPR
// at the TOP of iter i (covered by the whole iter's ds_read+MFMA, ~600 cyc,
// vs ~300 for the old mid-iter gl_lds16), then ds_written to the single LDS
// buffer after the read-barrier. The barrier's mandatory vmcnt(0) drain thus
// finds the loads already complete.
// LDS k-groups XOR-swizzled (phys_kg = kg ^ (row&7)): 0 bank conflicts.
#define BM 128
#define BN 64
#define BK 64

__global__ __launch_bounds__(256, 4)
void gemm_bt_kernel(const unsigned short* __restrict__ A,   // [M,K] bf16
                    const unsigned short* __restrict__ B,   // [N,K] bf16
                    const float* __restrict__ bias,         // [N]
                    float* __restrict__ C,                  // [M,N] f32
                    int M, int N, int K) {
    __shared__ unsigned short lds_a[BM * BK];   // 16 KB
    __shared__ unsigned short lds_b[BN * BK];   // 8 KB

    const int t      = threadIdx.x;
    const int lane   = t & 63;
    const int wave   = t >> 6;          // 0..3
    const int lane16 = lane & 15;
    const int quad   = lane >> 4;       // 0..3
    const int wm     = wave & 1;        // m-slot: 0..1 (64 rows each)
    const int wn     = wave >> 1;       // n-slot: 0..1 (32 cols each)

    const int m0 = blockIdx.y * BM;
    const int n0 = blockIdx.x * BN;

    // staging: A = 1024 chunks (rows 0..127), B = 512 chunks (rows 0..63);
    // 256 threads -> 4 A-chunks + 2 B-chunks each.
    // chunk c -> LDS slot c (row = c>>3, pkg = c&7); global kg = pkg ^ (row&7)
    const int pkg = t & 7;
    int arow[4], ago[4];
#pragma unroll
    for (int j = 0; j < 4; j++) {
        arow[j] = (j * 256 + t) >> 3;
        ago[j]  = (pkg ^ (arow[j] & 7)) * 8;
    }
    int brow[2], bgo[2];
#pragma unroll
    for (int j = 0; j < 2; j++) {
        brow[j] = (j * 256 + t) >> 3;
        bgo[j]  = (pkg ^ (brow[j] & 7)) * 8;
    }

    const unsigned short* Ab = A + (size_t)m0 * K;
    const unsigned short* Bb = B + (size_t)n0 * K;

    u32x4 ra[4], rb[2];
    auto load6 = [&](int k0) {
#pragma unroll
        for (int j = 0; j < 4; j++)
            ra[j] = *(const u32x4*)(Ab + (size_t)arow[j] * K + k0 + ago[j]);
#pragma unroll
        for (int j = 0; j < 2; j++)
            rb[j] = *(const u32x4*)(Bb + (size_t)brow[j] * K + k0 + bgo[j]);
    };
    auto write6 = [&]() {
#pragma unroll
        for (int j = 0; j < 4; j++)
            *(u32x4*)(lds_a + (j * 256 + t) * 8) = ra[j];
#pragma unroll
        for (int j = 0; j < 2; j++)
            *(u32x4*)(lds_b + (j * 256 + t) * 8) = rb[j];
    };

    f32x4 acc[4][2] = {};
    const int sw = lane16 & 7;   // read-side swizzle key
    const int nit = K / BK;      // 32

    // prologue: stage tile 0
    load6(0);
    write6();
    __syncthreads();

    for (int it = 0; it < nit; it++) {
        // (1) prefetch NEXT tile into registers (longest possible window)
        if (it + 1 < nit) load6((it + 1) * BK);

        // (2) hoist all fragment reads of current tile
        bf16x8 af[2][4], bfr[2][2];
#pragma unroll
        for (int ch = 0; ch < 2; ch++) {
            const int pk = ((ch * 4 + quad) ^ sw) * 8;
#pragma unroll
            for (int mi = 0; mi < 4; mi++)
                af[ch][mi] = *(const bf16x8*)(lds_a + (wm * 64 + mi * 16 + lane16) * BK + pk);
#pragma unroll
            for (int ni = 0; ni < 2; ni++)
                bfr[ch][ni] = *(const bf16x8*)(lds_b + (wn * 32 + ni * 16 + lane16) * BK + pk);
        }

        // (3) MFMAs
#pragma unroll
        for (int ch = 0; ch < 2; ch++)
#pragma unroll
            for (int mi = 0; mi < 4; mi++)
#pragma unroll
                for (int ni = 0; ni < 2; ni++)
                    acc[mi][ni] = __builtin_amdgcn_mfma_f32_16x16x32_bf16(
                        af[ch][mi], bfr[ch][ni], acc[mi][ni], 0, 0, 0);

        // (4) swap buffer contents: reads done -> write prefetched tile
        if (it + 1 < nit) {
            __syncthreads();     // all waves done reading current tile
            write6();            // regs were loaded a full iter ago
            __syncthreads();     // writes visible
        }
    }

    // epilogue: C/D layout col=lane&15, row=quad*4+reg (m89-verified)
    float bv[2];
#pragma unroll
    for (int ni = 0; ni < 2; ni++)
        bv[ni] = bias[n0 + wn * 32 + ni * 16 + lane16];

#pragma unroll
    for (int mi = 0; mi < 4; mi++) {
        const int rbase = m0 + wm * 64 + mi * 16 + quad * 4;
#pragma unroll
        for (int ni = 0; ni < 2; ni++) {
            const int col = n0 + wn * 32 + ni * 16 + lane16;
#pragma unroll
            for (int r = 0; r < 4; r++)
                C[(size_t)(rbase + r) * N + col] = acc[mi][ni][r] + bv[ni];
        }
    }
}

extern "C" void kernel_launch(void* const* d_in, const int* in_sizes, int n_in,
                              void* d_out, int out_size, void* d_ws, size_t ws_size,
                              hipStream_t stream) {
    const float* input = (const float*)d_in[0];
    const float* mu    = (const float*)d_in[1];
    const float* rho   = (const float*)d_in[2];
    const float* eps   = (const float*)d_in[3];
    const float* bias  = (const float*)d_in[4];
    float* out = (float*)d_out;

    const int OUT = in_sizes[4];              // 2048
    const int IN  = in_sizes[1] / OUT;        // 2048
    const int M   = in_sizes[0] / IN;         // 4096

    unsigned short* in_bf = (unsigned short*)d_ws;                 // M*IN bf16
    unsigned short* w_bf  = in_bf + (size_t)M * IN;                // OUT*IN bf16

    const int nIn8 = (M * IN) / 8;
    const int nW8  = (OUT * IN) / 8;
    prep_kernel<<<dim3((nIn8 + nW8 + 255) / 256), 256, 0, stream>>>(
        input, mu, rho, eps, in_bf, w_bf, nIn8, nW8);

    gemm_bt_kernel<<<dim3(OUT / BN, M / BM), 256, 0, stream>>>(
        in_bf, w_bf, bias, out, M, OUT, IN);
}